// Round 7
// baseline (990.632 us; speedup 1.0000x reference)
//
#include <hip/hip_runtime.h>
#include <hip/hip_cooperative_groups.h>
#include <stdint.h>

namespace cg = cooperative_groups;

typedef short bf16x8_t __attribute__((ext_vector_type(8)));
typedef short bf16x4_t __attribute__((ext_vector_type(4)));
typedef float f32x4_t __attribute__((ext_vector_type(4)));
typedef unsigned short u16x4_t __attribute__((ext_vector_type(4)));

#define DEV static __device__ __forceinline__

DEV float bf2f(unsigned short u) {
  union { unsigned int i; float f; } v; v.i = ((unsigned int)u) << 16; return v.f;
}
DEV unsigned short f2bf(float f) {
  union { float f; unsigned int i; } v; v.f = f;
  unsigned int x = v.i;
  unsigned int lsb = (x >> 16) & 1u;
  x += 0x7fffu + lsb;
  return (unsigned short)(x >> 16);
}

struct MegaArgs {
  const float* fsrc[10];       // x, Wm0..2, U0..2, V0..2 (fp32)
  unsigned short* fdst[10];    // xb, Wmb0..2, Ub0..2, Vb0..2 (bf16)
  const float* bm[3];
  const float* bb[3];
  unsigned short* xb;
  unsigned short* act;
  unsigned short* Wmb[3];
  unsigned short* Ub[3];
  unsigned short* Vb[3];
  unsigned short* hb;
  unsigned short* ug;
  float* ug_part;              // [8][8192][64] fp32
  float* out;
  int* counters;               // work-stealing counters (zeroed in-kernel)
};

// ---------------------------------------------------------------------------
// P0: convert all fp32 inputs to bf16 (grid-stride over 20864 virtual blocks)
DEV void phase_cvt(const MegaArgs& A, int bid, int tid, int NB) {
  const int bstart[11] = {0, 8192, 12288, 16384, 20480, 20544, 20608,
                          20672, 20736, 20800, 20864};
  for (int vb = bid; vb < 20864; vb += NB) {
    int seg = 0;
#pragma unroll
    for (int s = 1; s < 10; s++) seg += (vb >= bstart[s]) ? 1 : 0;
    int local = (vb - bstart[seg]) * 256 + tid;
    float4 v = ((const float4*)A.fsrc[seg])[local];
    u16x4_t o = { f2bf(v.x), f2bf(v.y), f2bf(v.z), f2bf(v.w) };
    *(u16x4_t*)&A.fdst[seg][local * 4] = o;
  }
}

// ---------------------------------------------------------------------------
// P1: u0 split-K, one virtual block = (slice = vb>>6 of 8, rowblock = vb&63)
DEV void u0_splitk_vb(const unsigned short* __restrict__ Acur,
                      const unsigned short* __restrict__ Ub,
                      float* __restrict__ part,
                      unsigned short* smem, int vb, int tid) {
  unsigned short* As = smem;            // 128*64
  unsigned short* Us = smem + 8192;     // 64*64
  const int lane = tid & 63;
  const int w = tid >> 6;
  const int ks = vb >> 6;
  const int rowBase = (vb & 63) * 128;
  const int kBase = ks * 128;
  const int rl = lane >> 3;
  const int kbg = (lane & 7) ^ rl;
  const int fr = lane & 15;
  const int quad = lane >> 4;

  f32x4_t acc[2][4];
#pragma unroll
  for (int i = 0; i < 2; i++)
#pragma unroll
    for (int j = 0; j < 4; j++) acc[i][j] = f32x4_t{0.f, 0.f, 0.f, 0.f};

  for (int kt = kBase; kt < kBase + 128; kt += 64) {
    __syncthreads();
#pragma unroll
    for (int jj = 0; jj < 4; ++jj) {
      int tr = w * 32 + jj * 8 + rl;
      const unsigned short* ga = Acur + (size_t)(rowBase + tr) * 1024 + kt + kbg * 8;
      __builtin_amdgcn_global_load_lds(
          (const __attribute__((address_space(1))) void*)ga,
          (__attribute__((address_space(3))) void*)&As[(w * 32 + jj * 8) * 64],
          16, 0, 0);
    }
#pragma unroll
    for (int jj = 0; jj < 2; ++jj) {
      int tr = w * 16 + jj * 8 + rl;
      const unsigned short* gu = Ub + (size_t)tr * 1024 + kt + kbg * 8;
      __builtin_amdgcn_global_load_lds(
          (const __attribute__((address_space(1))) void*)gu,
          (__attribute__((address_space(3))) void*)&Us[(w * 16 + jj * 8) * 64],
          16, 0, 0);
    }
    __syncthreads();

#pragma unroll
    for (int ksi = 0; ksi < 2; ++ksi) {
      bf16x8_t a[2], b[4];
#pragma unroll
      for (int i = 0; i < 2; i++) {
        int m = w * 32 + i * 16 + fr;
        int slot = (ksi * 4 + quad) ^ (m & 7);
        a[i] = *(const bf16x8_t*)&As[m * 64 + slot * 8];
      }
#pragma unroll
      for (int j = 0; j < 4; j++) {
        int n = j * 16 + fr;
        int slot = (ksi * 4 + quad) ^ (n & 7);
        b[j] = *(const bf16x8_t*)&Us[n * 64 + slot * 8];
      }
#pragma unroll
      for (int i = 0; i < 2; i++)
#pragma unroll
        for (int j = 0; j < 4; j++)
          acc[i][j] = __builtin_amdgcn_mfma_f32_16x16x32_bf16(a[i], b[j],
                                                              acc[i][j], 0, 0, 0);
    }
  }

  float* pp = part + ((size_t)ks * 8192 + rowBase) * 64;
#pragma unroll
  for (int i = 0; i < 2; i++)
#pragma unroll
    for (int j = 0; j < 4; j++)
#pragma unroll
      for (int r = 0; r < 4; r++) {
        int row = w * 32 + i * 16 + quad * 4 + r;
        pp[(size_t)row * 64 + j * 16 + fr] = acc[i][j][r];
      }
}

// P2: reduce 8 K-slices -> bf16 u (grid-stride over 512 virtual blocks)
DEV void phase_u0_reduce(const float* __restrict__ part,
                         unsigned short* __restrict__ ug,
                         int bid, int tid, int NB) {
  for (int vb = bid; vb < 512; vb += NB) {
    int i = vb * 256 + tid;  // vec4 idx over 131072
    f32x4_t s = {0.f, 0.f, 0.f, 0.f};
#pragma unroll
    for (int sl = 0; sl < 8; sl++)
      s += *(const f32x4_t*)&part[(i + sl * 131072) * 4];
    u16x4_t o = { f2bf(s[0]), f2bf(s[1]), f2bf(s[2]), f2bf(s[3]) };
    *(u16x4_t*)&ug[i * 4] = o;
  }
}

// ---------------------------------------------------------------------------
// P3: one fused hyper-GEMM tile + contraction (col' = s*64+r permutation).
// vb in [0,2048): bx = vb>>6 (col tile), by = vb&63 (row tile).
DEV void hyper_tile(const unsigned short* __restrict__ Acur,
                    const unsigned short* __restrict__ Wmb,
                    const unsigned short* __restrict__ ug,
                    const float* __restrict__ bm,
                    unsigned short* __restrict__ h_out,
                    unsigned short* smem, int vb, int tid) {
  const int lane = tid & 63;
  const int w = tid >> 6;
  const int wrow0 = (w & 1) * 64;
  const int wcol0 = (w >> 1) * 64;
  const int rl = lane >> 3;
  const int kbg = (lane & 7) ^ rl;
  const int fr = lane & 15;
  const int quad = lane >> 4;
  unsigned short* As = smem;
  unsigned short* Bs = smem + 8192;

  const int bx = vb >> 6;
  const int by = vb & 63;
  const int rowBase = by * 128;
  const int colBase = bx * 128;

  f32x4_t acc[4][4];
#pragma unroll
  for (int i = 0; i < 4; i++)
#pragma unroll
    for (int j = 0; j < 4; j++) acc[i][j] = f32x4_t{0.f, 0.f, 0.f, 0.f};

  for (int kt = 0; kt < 1024; kt += 64) {
    __syncthreads();
#pragma unroll
    for (int jj = 0; jj < 4; ++jj) {
      int tr = w * 32 + jj * 8 + rl;
      int ct = colBase + tr;
      int pr = ((ct & 63) << 6) | (ct >> 6);  // Wm row for hyper-col ct
      const unsigned short* ga = Acur + (size_t)(rowBase + tr) * 1024 + kt + kbg * 8;
      const unsigned short* gb = Wmb + (size_t)pr * 1024 + kt + kbg * 8;
      __builtin_amdgcn_global_load_lds(
          (const __attribute__((address_space(1))) void*)ga,
          (__attribute__((address_space(3))) void*)&As[(w * 32 + jj * 8) * 64],
          16, 0, 0);
      __builtin_amdgcn_global_load_lds(
          (const __attribute__((address_space(1))) void*)gb,
          (__attribute__((address_space(3))) void*)&Bs[(w * 32 + jj * 8) * 64],
          16, 0, 0);
    }
    __syncthreads();

#pragma unroll
    for (int ks = 0; ks < 2; ++ks) {
      bf16x8_t a[4], b[4];
#pragma unroll
      for (int i = 0; i < 4; i++) {
        int m = wrow0 + i * 16 + fr;
        int slot = (ks * 4 + quad) ^ (m & 7);
        a[i] = *(const bf16x8_t*)&As[m * 64 + slot * 8];
      }
#pragma unroll
      for (int j = 0; j < 4; j++) {
        int n = wcol0 + j * 16 + fr;
        int slot = (ks * 4 + quad) ^ (n & 7);
        b[j] = *(const bf16x8_t*)&Bs[n * 64 + slot * 8];
      }
#pragma unroll
      for (int i = 0; i < 4; i++)
#pragma unroll
        for (int j = 0; j < 4; j++)
          acc[i][j] = __builtin_amdgcn_mfma_f32_16x16x32_bf16(a[i], b[j],
                                                              acc[i][j], 0, 0, 0);
    }
  }

  // fused contraction epilogue
  __syncthreads();
  {
    int row = tid >> 1;
    int c0 = (tid & 1) * 32;
    const unsigned short* up = ug + (size_t)(rowBase + row) * 64 + c0;
    bf16x8_t v0 = *(const bf16x8_t*)(up);
    bf16x8_t v1 = *(const bf16x8_t*)(up + 8);
    bf16x8_t v2 = *(const bf16x8_t*)(up + 16);
    bf16x8_t v3 = *(const bf16x8_t*)(up + 24);
#pragma unroll
    for (int m = 0; m < 8; m++) {
      smem[(c0 + m) * 136 + row] = (unsigned short)v0[m];
      smem[(c0 + 8 + m) * 136 + row] = (unsigned short)v1[m];
      smem[(c0 + 16 + m) * 136 + row] = (unsigned short)v2[m];
      smem[(c0 + 24 + m) * 136 + row] = (unsigned short)v3[m];
    }
  }
  __syncthreads();

  const int s = bx * 2 + (w >> 1);
  float bmv[4];
#pragma unroll
  for (int j = 0; j < 4; j++) bmv[j] = bm[(j * 16 + fr) * 64 + s];

#pragma unroll
  for (int i = 0; i < 4; i++) {
    int row0 = wrow0 + i * 16 + quad * 4;
    bf16x4_t uv[4];
#pragma unroll
    for (int j = 0; j < 4; j++)
      uv[j] = *(const bf16x4_t*)&smem[(j * 16 + fr) * 136 + row0];
#pragma unroll
    for (int r = 0; r < 4; r++) {
      float p = 0.f;
#pragma unroll
      for (int j = 0; j < 4; j++)
        p += bf2f((unsigned short)uv[j][r]) * (acc[i][j][r] + bmv[j]);
      p += __shfl_xor(p, 1, 64);
      p += __shfl_xor(p, 2, 64);
      p += __shfl_xor(p, 4, 64);
      p += __shfl_xor(p, 8, 64);
      if (fr == 0)
        h_out[(size_t)(rowBase + row0 + r) * 64 + s] = f2bf(p);
    }
  }
}

// ---------------------------------------------------------------------------
// P4: one fused V-GEMM + next-layer u-GEMM virtual block (16 sample rows).
DEV void vu_vb(const unsigned short* __restrict__ h,
               const unsigned short* __restrict__ Vb,
               const float* __restrict__ bias,
               const unsigned short* __restrict__ Un,
               unsigned short* __restrict__ act,
               unsigned short* __restrict__ u_out,
               unsigned char* smem_raw, int vb, int tid) {
  unsigned short* tlds = (unsigned short*)smem_raw;       // 4*16*72 shorts
  float* upart = (float*)(smem_raw + 9216);               // 4*16*68 floats

  const int lane = tid & 63;
  const int w = tid >> 6;
  const int fr = lane & 15;
  const int quad = lane >> 4;
  const int rowBase = vb * 16;

  __syncthreads();  // upart/tlds reuse across virtual blocks

  unsigned short* tl = &tlds[w * 16 * 72];

  bf16x8_t ah0 = *(const bf16x8_t*)&h[(size_t)(rowBase + fr) * 64 + quad * 8];
  bf16x8_t ah1 = *(const bf16x8_t*)&h[(size_t)(rowBase + fr) * 64 + 32 + quad * 8];

  f32x4_t uacc[4];
#pragma unroll
  for (int n = 0; n < 4; n++) uacc[n] = f32x4_t{0.f, 0.f, 0.f, 0.f};

  for (int it = 0; it < 4; ++it) {
    const int cb = w * 256 + it * 64;

    f32x4_t tacc[4];
#pragma unroll
    for (int nt = 0; nt < 4; nt++) {
      const unsigned short* vrow = Vb + (size_t)(cb + nt * 16 + fr) * 64;
      bf16x8_t b0 = *(const bf16x8_t*)&vrow[quad * 8];
      bf16x8_t b1 = *(const bf16x8_t*)&vrow[32 + quad * 8];
      f32x4_t z = {0.f, 0.f, 0.f, 0.f};
      z = __builtin_amdgcn_mfma_f32_16x16x32_bf16(ah0, b0, z, 0, 0, 0);
      tacc[nt] = __builtin_amdgcn_mfma_f32_16x16x32_bf16(ah1, b1, z, 0, 0, 0);
    }

#pragma unroll
    for (int nt = 0; nt < 4; nt++) {
      float bv = bias[cb + nt * 16 + fr];
#pragma unroll
      for (int r = 0; r < 4; r++) {
        float v = tacc[nt][r] + bv;
        v = v > 0.f ? v : 0.f;
        tl[(quad * 4 + r) * 72 + nt * 16 + fr] = f2bf(v);
      }
    }

    {
      int m2 = lane >> 2;
      int kc = (lane & 3) * 16;
      bf16x8_t t0 = *(const bf16x8_t*)&tl[m2 * 72 + kc];
      bf16x8_t t1 = *(const bf16x8_t*)&tl[m2 * 72 + kc + 8];
      unsigned short* ap = act + (size_t)(rowBase + m2) * 1024 + cb + kc;
      *(bf16x8_t*)ap = t0;
      *(bf16x8_t*)(ap + 8) = t1;
    }

#pragma unroll
    for (int ks = 0; ks < 2; ++ks) {
      bf16x8_t at = *(const bf16x8_t*)&tl[fr * 72 + ks * 32 + quad * 8];
#pragma unroll
      for (int n = 0; n < 4; n++) {
        bf16x8_t bu = *(const bf16x8_t*)&Un[(size_t)(n * 16 + fr) * 1024 + cb +
                                            ks * 32 + quad * 8];
        uacc[n] = __builtin_amdgcn_mfma_f32_16x16x32_bf16(at, bu, uacc[n], 0, 0, 0);
      }
    }
  }

  {
    float* up = &upart[w * 16 * 68];
#pragma unroll
    for (int n = 0; n < 4; n++)
#pragma unroll
      for (int r = 0; r < 4; r++)
        up[(quad * 4 + r) * 68 + n * 16 + fr] = uacc[n][r];
  }
  __syncthreads();
  {
    int m = tid >> 4;
    int c0 = (tid & 15) * 4;
    f32x4_t s = {0.f, 0.f, 0.f, 0.f};
#pragma unroll
    for (int wv = 0; wv < 4; wv++)
      s += *(const f32x4_t*)&upart[wv * 16 * 68 + m * 68 + c0];
    u16x4_t o = { f2bf(s[0]), f2bf(s[1]), f2bf(s[2]), f2bf(s[3]) };
    *(u16x4_t*)&u_out[(size_t)(rowBase + m) * 64 + c0] = o;
  }
}

// ---------------------------------------------------------------------------
// P5: final out = h @ V^T + b (fp32), one 128x128 tile per virtual block
DEV void final_vb(const unsigned short* __restrict__ Ah,
                  const unsigned short* __restrict__ Bv,
                  const float* __restrict__ bias,
                  float* __restrict__ Cout,
                  unsigned short* smem, int vb, int tid) {
  unsigned short* As = smem;
  unsigned short* Bs = smem + 8192;
  const int lane = tid & 63;
  const int w = tid >> 6;
  const int wrow0 = (w & 1) * 64;
  const int wcol0 = (w >> 1) * 64;
  const int rowBase = (vb & 63) * 128;
  const int colBase = (vb >> 6) * 128;
  const int rl = lane >> 3;
  const int kbg = (lane & 7) ^ rl;
  const int fr = lane & 15;
  const int quad = lane >> 4;

  f32x4_t acc[4][4];
#pragma unroll
  for (int i = 0; i < 4; i++)
#pragma unroll
    for (int j = 0; j < 4; j++) acc[i][j] = f32x4_t{0.f, 0.f, 0.f, 0.f};

  __syncthreads();
#pragma unroll
  for (int jj = 0; jj < 4; ++jj) {
    int tr = w * 32 + jj * 8 + rl;
    const unsigned short* ga = Ah + (size_t)(rowBase + tr) * 64 + kbg * 8;
    const unsigned short* gb = Bv + (size_t)(colBase + tr) * 64 + kbg * 8;
    __builtin_amdgcn_global_load_lds(
        (const __attribute__((address_space(1))) void*)ga,
        (__attribute__((address_space(3))) void*)&As[(w * 32 + jj * 8) * 64],
        16, 0, 0);
    __builtin_amdgcn_global_load_lds(
        (const __attribute__((address_space(1))) void*)gb,
        (__attribute__((address_space(3))) void*)&Bs[(w * 32 + jj * 8) * 64],
        16, 0, 0);
  }
  __syncthreads();

#pragma unroll
  for (int ks = 0; ks < 2; ++ks) {
    bf16x8_t a[4], b[4];
#pragma unroll
    for (int i = 0; i < 4; i++) {
      int m = wrow0 + i * 16 + fr;
      int slot = (ks * 4 + quad) ^ (m & 7);
      a[i] = *(const bf16x8_t*)&As[m * 64 + slot * 8];
    }
#pragma unroll
    for (int j = 0; j < 4; j++) {
      int n = wcol0 + j * 16 + fr;
      int slot = (ks * 4 + quad) ^ (n & 7);
      b[j] = *(const bf16x8_t*)&Bs[n * 64 + slot * 8];
    }
#pragma unroll
    for (int i = 0; i < 4; i++)
#pragma unroll
      for (int j = 0; j < 4; j++)
        acc[i][j] = __builtin_amdgcn_mfma_f32_16x16x32_bf16(a[i], b[j],
                                                            acc[i][j], 0, 0, 0);
  }

#pragma unroll
  for (int j = 0; j < 4; j++) {
    int col = colBase + wcol0 + j * 16 + fr;
    float bv = bias[col];
#pragma unroll
    for (int i = 0; i < 4; i++) {
#pragma unroll
      for (int r = 0; r < 4; r++) {
        int row = rowBase + wrow0 + i * 16 + quad * 4 + r;
        Cout[(size_t)row * 1024 + col] = acc[i][j][r] + bv;
      }
    }
  }
}

// ---------------------------------------------------------------------------
// Cooperative mega-kernel: all phases, grid barriers between, work-stealing
// for the hyper tiles. Any gridDim >= 1 is correct.
__global__ __launch_bounds__(256, 2) void mega_k(MegaArgs A) {
  __shared__ alignas(16) unsigned char smem_raw[32768];
  __shared__ int s_tile;
  unsigned short* smem = (unsigned short*)smem_raw;
  cg::grid_group g = cg::this_grid();
  const int bid = blockIdx.x;
  const int tid = threadIdx.x;
  const int NB = gridDim.x;

  if (bid == 0 && tid < 8) A.counters[tid] = 0;

  phase_cvt(A, bid, tid, NB);
  g.sync();

  for (int vb = bid; vb < 512; vb += NB)
    u0_splitk_vb(A.xb, A.Ub[0], A.ug_part, smem, vb, tid);
  g.sync();

  phase_u0_reduce(A.ug_part, A.ug, bid, tid, NB);
  g.sync();

  const unsigned short* cur = A.xb;
#pragma unroll 1
  for (int l = 0; l < 3; l++) {
    // hyper tiles via work stealing (2048 tiles, bx-major for B-tile L2 share)
    for (;;) {
      if (tid == 0) s_tile = atomicAdd(&A.counters[l], 1);
      __syncthreads();
      int vb = s_tile;
      __syncthreads();
      if (vb >= 2048) break;
      hyper_tile(cur, A.Wmb[l], A.ug, A.bm[l], A.hb, smem, vb, tid);
    }
    g.sync();

    if (l < 2) {
      for (int vb = bid; vb < 512; vb += NB)
        vu_vb(A.hb, A.Vb[l], A.bb[l], A.Ub[l + 1], A.act, A.ug, smem_raw, vb, tid);
      g.sync();
      cur = A.act;
    } else {
      for (int vb = bid; vb < 512; vb += NB)
        final_vb(A.hb, A.Vb[2], A.bb[2], A.out, smem, vb, tid);
    }
  }
}

// ---------------------------------------------------------------------------
// Fallback wrappers (ordinary launches, r4-equivalent path)
__global__ __launch_bounds__(256) void k_cvt(MegaArgs A) {
  phase_cvt(A, blockIdx.x, threadIdx.x, gridDim.x);
}
__global__ __launch_bounds__(256, 2) void k_u0_splitk(MegaArgs A) {
  __shared__ unsigned short smem[12288];
  for (int vb = blockIdx.x; vb < 512; vb += gridDim.x)
    u0_splitk_vb(A.xb, A.Ub[0], A.ug_part, smem, vb, threadIdx.x);
}
__global__ __launch_bounds__(256) void k_u0_reduce(MegaArgs A) {
  phase_u0_reduce(A.ug_part, A.ug, blockIdx.x, threadIdx.x, gridDim.x);
}
__global__ __launch_bounds__(256, 2) void k_hyper(
    const unsigned short* __restrict__ Acur,
    const unsigned short* __restrict__ Wmb,
    const unsigned short* __restrict__ ug, const float* __restrict__ bm,
    unsigned short* __restrict__ hb) {
  __shared__ unsigned short smem[16384];
  hyper_tile(Acur, Wmb, ug, bm, hb, smem, blockIdx.x, threadIdx.x);
}
__global__ __launch_bounds__(256, 2) void k_vu(
    const unsigned short* __restrict__ h, const unsigned short* __restrict__ Vb,
    const float* __restrict__ bias, const unsigned short* __restrict__ Un,
    unsigned short* __restrict__ act, unsigned short* __restrict__ u_out) {
  __shared__ alignas(16) unsigned char smem_raw[28672];
  vu_vb(h, Vb, bias, Un, act, u_out, smem_raw, blockIdx.x, threadIdx.x);
}
__global__ __launch_bounds__(256, 2) void k_final(
    const unsigned short* __restrict__ Ah, const unsigned short* __restrict__ Bv,
    const float* __restrict__ bias, float* __restrict__ Cout) {
  __shared__ unsigned short smem[12288];
  final_vb(Ah, Bv, bias, Cout, smem, blockIdx.x, threadIdx.x);
}

// ---------------------------------------------------------------------------
extern "C" void kernel_launch(void* const* d_in, const int* in_sizes, int n_in,
                              void* d_out, int out_size, void* d_ws,
                              size_t ws_size, hipStream_t stream) {
  const float* x = (const float*)d_in[0];
  const float* Wm[3] = {(const float*)d_in[1], (const float*)d_in[6], (const float*)d_in[11]};
  const float* bm[3] = {(const float*)d_in[2], (const float*)d_in[7], (const float*)d_in[12]};
  const float* U[3]  = {(const float*)d_in[3], (const float*)d_in[8], (const float*)d_in[13]};
  const float* V[3]  = {(const float*)d_in[4], (const float*)d_in[9], (const float*)d_in[14]};
  const float* bs[3] = {(const float*)d_in[5], (const float*)d_in[10], (const float*)d_in[15]};

  char* p = (char*)d_ws;
  unsigned short* xb = (unsigned short*)p;  p += 8192UL * 1024 * 2;
  unsigned short* act = (unsigned short*)p; p += 8192UL * 1024 * 2;
  unsigned short* Wmb[3];
  for (int l = 0; l < 3; l++) { Wmb[l] = (unsigned short*)p; p += 4096UL * 1024 * 2; }
  unsigned short* Ub[3];
  for (int l = 0; l < 3; l++) { Ub[l] = (unsigned short*)p; p += 64UL * 1024 * 2; }
  unsigned short* Vb[3];
  for (int l = 0; l < 3; l++) { Vb[l] = (unsigned short*)p; p += 1024UL * 64 * 2; }
  unsigned short* hb = (unsigned short*)p;  p += 8192UL * 64 * 2;
  unsigned short* ug = (unsigned short*)p;  p += 8192UL * 64 * 2;
  float* ug_part = (float*)p;               p += 8UL * 8192 * 64 * 4;
  int* counters = (int*)p;                  p += 64;

  MegaArgs A;
  A.fsrc[0] = x;  A.fdst[0] = xb;
  for (int l = 0; l < 3; l++) { A.fsrc[1 + l] = Wm[l]; A.fdst[1 + l] = Wmb[l]; }
  for (int l = 0; l < 3; l++) { A.fsrc[4 + l] = U[l];  A.fdst[4 + l] = Ub[l]; }
  for (int l = 0; l < 3; l++) { A.fsrc[7 + l] = V[l];  A.fdst[7 + l] = Vb[l]; }
  for (int l = 0; l < 3; l++) {
    A.bm[l] = bm[l]; A.bb[l] = bs[l];
    A.Wmb[l] = Wmb[l]; A.Ub[l] = Ub[l]; A.Vb[l] = Vb[l];
  }
  A.xb = xb; A.act = act; A.hb = hb; A.ug = ug;
  A.ug_part = ug_part; A.out = (float*)d_out; A.counters = counters;

  // ---- cooperative path: query achievable co-residency, launch accordingly
  int maxPerCU = 0;
  (void)hipOccupancyMaxActiveBlocksPerMultiprocessor(&maxPerCU, mega_k, 256, 0);
  int numCU = 256;
  {
    int dev = 0;
    (void)hipGetDevice(&dev);
    (void)hipDeviceGetAttribute(&numCU, hipDeviceAttributeMultiprocessorCount,
                                dev);
  }
  bool coop_done = false;
  if (maxPerCU >= 1) {
    long cap = (long)maxPerCU * numCU;
    int NB = (int)(cap < 768 ? cap : 768);
    if (NB >= 256) {
      void* kargs[] = {(void*)&A};
      hipError_t e = hipLaunchCooperativeKernel(mega_k, dim3(NB), dim3(256),
                                                kargs, 0u, stream);
      coop_done = (e == hipSuccess);
    }
  }

  // ---- fallback: ordinary multi-kernel path (r4-equivalent)
  if (!coop_done) {
    k_cvt<<<20864, 256, 0, stream>>>(A);
    k_u0_splitk<<<512, 256, 0, stream>>>(A);
    k_u0_reduce<<<512, 256, 0, stream>>>(A);
    const unsigned short* cur = xb;
    for (int l = 0; l < 3; l++) {
      k_hyper<<<2048, 256, 0, stream>>>(cur, Wmb[l], ug, bm[l], hb);
      if (l < 2) {
        k_vu<<<512, 256, 0, stream>>>(hb, Vb[l], bs[l], Ub[l + 1], act, ug);
        cur = act;
      } else {
        k_final<<<512, 256, 0, stream>>>(hb, Vb[2], bs[2], (float*)d_out);
      }
    }
  }
}

// Round 8
// 415.816 us; speedup vs baseline: 2.3824x; 2.3824x over previous
//
#include <hip/hip_runtime.h>
#include <stdint.h>

typedef short bf16x8_t __attribute__((ext_vector_type(8)));
typedef short bf16x4_t __attribute__((ext_vector_type(4)));
typedef float f32x4_t __attribute__((ext_vector_type(4)));
typedef unsigned short u16x4_t __attribute__((ext_vector_type(4)));

#define DEV static __device__ __forceinline__

DEV float bf2f(unsigned short u) {
  union { unsigned int i; float f; } v; v.i = ((unsigned int)u) << 16; return v.f;
}
DEV unsigned short f2bf(float f) {
  union { float f; unsigned int i; } v; v.f = f;
  unsigned int x = v.i;
  unsigned int lsb = (x >> 16) & 1u;
  x += 0x7fffu + lsb;
  return (unsigned short)(x >> 16);
}

// Up to 3 cvt segments; boundaries in blocks of 256 vec4s (block-uniform).
struct CvtSeg {
  const float* src[3];
  unsigned short* dst[3];
  int bstart[4];   // bstart[0]=0; bstart[3]=total blocks
};

DEV void cvt_block(const CvtSeg& cs, int vb, int tid) {
  int seg = (vb >= cs.bstart[1] ? 1 : 0) + (vb >= cs.bstart[2] ? 1 : 0);
  int local = (vb - cs.bstart[seg]) * 256 + tid;
  float4 v = ((const float4*)cs.src[seg])[local];
  u16x4_t o = { f2bf(v.x), f2bf(v.y), f2bf(v.z), f2bf(v.w) };
  *(u16x4_t*)&cs.dst[seg][local * 4] = o;
}

// ---------------------------------------------------------------------------
// Dispatch 1: convert x, Wm0, U0 (the only conversions on the critical path)
__global__ __launch_bounds__(256) void k_cvt(CvtSeg cs) {
  cvt_block(cs, blockIdx.x, threadIdx.x);
}

// ---------------------------------------------------------------------------
// Split-K u-GEMM (layer 0): part[kslice] = A-rows @ U^T over a K-slice of 256.
__global__ __launch_bounds__(256, 2) void u_splitk(
    const unsigned short* __restrict__ A,   // [8192 x 1024] bf16
    const unsigned short* __restrict__ Ub,  // [64 x 1024] bf16
    float* __restrict__ part) {             // [4][8192][64] fp32
  __shared__ unsigned short As[128 * 64];
  __shared__ unsigned short Us[64 * 64];

  const int tid = threadIdx.x;
  const int lane = tid & 63;
  const int w = tid >> 6;
  const int rowBase = blockIdx.y * 128;
  const int kBase = blockIdx.x * 256;

  const int rl = lane >> 3;
  const int kbg = (lane & 7) ^ rl;
  const int fr = lane & 15;
  const int quad = lane >> 4;

  f32x4_t acc[2][4];
#pragma unroll
  for (int i = 0; i < 2; i++)
#pragma unroll
    for (int j = 0; j < 4; j++) acc[i][j] = f32x4_t{0.f, 0.f, 0.f, 0.f};

  for (int kt = kBase; kt < kBase + 256; kt += 64) {
    __syncthreads();
#pragma unroll
    for (int jj = 0; jj < 4; ++jj) {
      int tr = w * 32 + jj * 8 + rl;
      const unsigned short* ga = A + (size_t)(rowBase + tr) * 1024 + kt + kbg * 8;
      __builtin_amdgcn_global_load_lds(
          (const __attribute__((address_space(1))) void*)ga,
          (__attribute__((address_space(3))) void*)&As[(w * 32 + jj * 8) * 64],
          16, 0, 0);
    }
#pragma unroll
    for (int jj = 0; jj < 2; ++jj) {
      int tr = w * 16 + jj * 8 + rl;
      const unsigned short* gu = Ub + (size_t)tr * 1024 + kt + kbg * 8;
      __builtin_amdgcn_global_load_lds(
          (const __attribute__((address_space(1))) void*)gu,
          (__attribute__((address_space(3))) void*)&Us[(w * 16 + jj * 8) * 64],
          16, 0, 0);
    }
    __syncthreads();

#pragma unroll
    for (int ks = 0; ks < 2; ++ks) {
      bf16x8_t a[2], b[4];
#pragma unroll
      for (int i = 0; i < 2; i++) {
        int m = w * 32 + i * 16 + fr;
        int slot = (ks * 4 + quad) ^ (m & 7);
        a[i] = *(const bf16x8_t*)&As[m * 64 + slot * 8];
      }
#pragma unroll
      for (int j = 0; j < 4; j++) {
        int n = j * 16 + fr;
        int slot = (ks * 4 + quad) ^ (n & 7);
        b[j] = *(const bf16x8_t*)&Us[n * 64 + slot * 8];
      }
#pragma unroll
      for (int i = 0; i < 2; i++)
#pragma unroll
        for (int j = 0; j < 4; j++)
          acc[i][j] = __builtin_amdgcn_mfma_f32_16x16x32_bf16(a[i], b[j],
                                                              acc[i][j], 0, 0, 0);
    }
  }

  float* pp = part + ((size_t)blockIdx.x * 8192 + rowBase) * 64;
#pragma unroll
  for (int i = 0; i < 2; i++)
#pragma unroll
    for (int j = 0; j < 4; j++)
#pragma unroll
      for (int r = 0; r < 4; r++) {
        int row = w * 32 + i * 16 + quad * 4 + r;
        pp[(size_t)row * 64 + j * 16 + fr] = acc[i][j][r];
      }
}

// sum 4 K-slices -> bf16 u [8192 x 64]
__global__ __launch_bounds__(256) void u_reduce_k(
    const float* __restrict__ part, unsigned short* __restrict__ ug) {
  int i = blockIdx.x * 256 + threadIdx.x;  // vec4 idx over 131072
  float4 s0 = ((const float4*)part)[i];
  float4 s1 = ((const float4*)part)[i + 131072];
  float4 s2 = ((const float4*)part)[i + 262144];
  float4 s3 = ((const float4*)part)[i + 393216];
  u16x4_t o = { f2bf(s0.x + s1.x + s2.x + s3.x),
                f2bf(s0.y + s1.y + s2.y + s3.y),
                f2bf(s0.z + s1.z + s2.z + s3.z),
                f2bf(s0.w + s1.w + s2.w + s3.w) };
  *(u16x4_t*)&ug[i * 4] = o;
}

// ---------------------------------------------------------------------------
// Fused hyper-GEMM + per-sample contraction (col' = s*64+r permutation),
// PLUS appended cvt blocks (blockIdx.x >= 2048) converting the NEXT layer's
// weights while the GEMM runs — hides conversion under the GEMM tail.
// Tile mapping matches r4's dim3(32,64): bx = vb & 31, by = vb >> 5.
__global__ __launch_bounds__(256, 2) void k_hyper(
    const unsigned short* __restrict__ A,    // [8192 x 1024] bf16
    const unsigned short* __restrict__ Wmb,  // [4096 x 1024] bf16
    const unsigned short* __restrict__ ug,   // [8192 x 64] bf16
    const float* __restrict__ bm,            // [4096] fp32
    unsigned short* __restrict__ h_out,      // [8192 x 64] bf16
    CvtSeg cs) {
  __shared__ unsigned short smem[16384];

  if (blockIdx.x >= 2048) {                  // appended conversion work
    cvt_block(cs, blockIdx.x - 2048, threadIdx.x);
    return;
  }

  unsigned short* As = smem;
  unsigned short* Bs = smem + 8192;
  const int K = 1024;

  const int tid = threadIdx.x;
  const int lane = tid & 63;
  const int w = tid >> 6;
  const int wrow0 = (w & 1) * 64;
  const int wcol0 = (w >> 1) * 64;
  const int bx = blockIdx.x & 31;
  const int by = blockIdx.x >> 5;
  const int rowBase = by * 128;
  const int colBase = bx * 128;

  const int rl = lane >> 3;
  const int kbg = (lane & 7) ^ rl;
  const int fr = lane & 15;
  const int quad = lane >> 4;

  f32x4_t acc[4][4];
#pragma unroll
  for (int i = 0; i < 4; i++)
#pragma unroll
    for (int j = 0; j < 4; j++) acc[i][j] = f32x4_t{0.f, 0.f, 0.f, 0.f};

  for (int kt = 0; kt < K; kt += 64) {
    __syncthreads();
#pragma unroll
    for (int jj = 0; jj < 4; ++jj) {
      int tr = w * 32 + jj * 8 + rl;
      int ct = colBase + tr;
      int pr = ((ct & 63) << 6) | (ct >> 6);  // Wm row for hyper-col ct
      const unsigned short* ga = A + (size_t)(rowBase + tr) * K + kt + kbg * 8;
      const unsigned short* gb = Wmb + (size_t)pr * K + kt + kbg * 8;
      __builtin_amdgcn_global_load_lds(
          (const __attribute__((address_space(1))) void*)ga,
          (__attribute__((address_space(3))) void*)&As[(w * 32 + jj * 8) * 64],
          16, 0, 0);
      __builtin_amdgcn_global_load_lds(
          (const __attribute__((address_space(1))) void*)gb,
          (__attribute__((address_space(3))) void*)&Bs[(w * 32 + jj * 8) * 64],
          16, 0, 0);
    }
    __syncthreads();

#pragma unroll
    for (int ks = 0; ks < 2; ++ks) {
      bf16x8_t a[4], b[4];
#pragma unroll
      for (int i = 0; i < 4; i++) {
        int m = wrow0 + i * 16 + fr;
        int slot = (ks * 4 + quad) ^ (m & 7);
        a[i] = *(const bf16x8_t*)&As[m * 64 + slot * 8];
      }
#pragma unroll
      for (int j = 0; j < 4; j++) {
        int n = wcol0 + j * 16 + fr;
        int slot = (ks * 4 + quad) ^ (n & 7);
        b[j] = *(const bf16x8_t*)&Bs[n * 64 + slot * 8];
      }
#pragma unroll
      for (int i = 0; i < 4; i++)
#pragma unroll
        for (int j = 0; j < 4; j++)
          acc[i][j] = __builtin_amdgcn_mfma_f32_16x16x32_bf16(a[i], b[j],
                                                              acc[i][j], 0, 0, 0);
    }
  }

  // ---- fused contraction epilogue ----
  __syncthreads();

  // stage u transposed: u_t[r][row], stride 136 to spread banks
  {
    int row = tid >> 1;
    int c0 = (tid & 1) * 32;
    const unsigned short* up = ug + (size_t)(rowBase + row) * 64 + c0;
    bf16x8_t v0 = *(const bf16x8_t*)(up);
    bf16x8_t v1 = *(const bf16x8_t*)(up + 8);
    bf16x8_t v2 = *(const bf16x8_t*)(up + 16);
    bf16x8_t v3 = *(const bf16x8_t*)(up + 24);
#pragma unroll
    for (int m = 0; m < 8; m++) {
      smem[(c0 + m) * 136 + row] = (unsigned short)v0[m];
      smem[(c0 + 8 + m) * 136 + row] = (unsigned short)v1[m];
      smem[(c0 + 16 + m) * 136 + row] = (unsigned short)v2[m];
      smem[(c0 + 24 + m) * 136 + row] = (unsigned short)v3[m];
    }
  }
  __syncthreads();

  const int s = bx * 2 + (w >> 1);
  float bmv[4];
#pragma unroll
  for (int j = 0; j < 4; j++) bmv[j] = bm[(j * 16 + fr) * 64 + s];

#pragma unroll
  for (int i = 0; i < 4; i++) {
    int row0 = wrow0 + i * 16 + quad * 4;
    bf16x4_t uv[4];
#pragma unroll
    for (int j = 0; j < 4; j++)
      uv[j] = *(const bf16x4_t*)&smem[(j * 16 + fr) * 136 + row0];
#pragma unroll
    for (int r = 0; r < 4; r++) {
      float p = 0.f;
#pragma unroll
      for (int j = 0; j < 4; j++)
        p += bf2f((unsigned short)uv[j][r]) * (acc[i][j][r] + bmv[j]);
      p += __shfl_xor(p, 1, 64);
      p += __shfl_xor(p, 2, 64);
      p += __shfl_xor(p, 4, 64);
      p += __shfl_xor(p, 8, 64);
      if (fr == 0)
        h_out[(size_t)(rowBase + row0 + r) * 64 + s] = f2bf(p);
    }
  }
}

// ---------------------------------------------------------------------------
// Fused V-GEMM + next-layer u-GEMM (r4-proven).
__global__ __launch_bounds__(256, 2) void vu_fused(
    const unsigned short* __restrict__ h,    // [8192 x 64] bf16
    const unsigned short* __restrict__ Vb,   // [1024 x 64] bf16
    const float* __restrict__ bias,          // [1024] fp32
    const unsigned short* __restrict__ Un,   // [64 x 1024] bf16 (next U)
    unsigned short* __restrict__ act,        // [8192 x 1024] bf16
    unsigned short* __restrict__ u_out) {    // [8192 x 64] bf16
  __shared__ unsigned short tlds[4 * 16 * 72];
  __shared__ float upart[4 * 16 * 68];

  const int tid = threadIdx.x;
  const int lane = tid & 63;
  const int w = tid >> 6;
  const int fr = lane & 15;
  const int quad = lane >> 4;
  const int rowBase = blockIdx.x * 16;

  unsigned short* tl = &tlds[w * 16 * 72];

  bf16x8_t ah0 = *(const bf16x8_t*)&h[(size_t)(rowBase + fr) * 64 + quad * 8];
  bf16x8_t ah1 = *(const bf16x8_t*)&h[(size_t)(rowBase + fr) * 64 + 32 + quad * 8];

  f32x4_t uacc[4];
#pragma unroll
  for (int n = 0; n < 4; n++) uacc[n] = f32x4_t{0.f, 0.f, 0.f, 0.f};

  for (int it = 0; it < 4; ++it) {
    const int cb = w * 256 + it * 64;

    f32x4_t tacc[4];
#pragma unroll
    for (int nt = 0; nt < 4; nt++) {
      const unsigned short* vrow = Vb + (size_t)(cb + nt * 16 + fr) * 64;
      bf16x8_t b0 = *(const bf16x8_t*)&vrow[quad * 8];
      bf16x8_t b1 = *(const bf16x8_t*)&vrow[32 + quad * 8];
      f32x4_t z = {0.f, 0.f, 0.f, 0.f};
      z = __builtin_amdgcn_mfma_f32_16x16x32_bf16(ah0, b0, z, 0, 0, 0);
      tacc[nt] = __builtin_amdgcn_mfma_f32_16x16x32_bf16(ah1, b1, z, 0, 0, 0);
    }

#pragma unroll
    for (int nt = 0; nt < 4; nt++) {
      float bv = bias[cb + nt * 16 + fr];
#pragma unroll
      for (int r = 0; r < 4; r++) {
        float v = tacc[nt][r] + bv;
        v = v > 0.f ? v : 0.f;
        tl[(quad * 4 + r) * 72 + nt * 16 + fr] = f2bf(v);
      }
    }

    {
      int m2 = lane >> 2;
      int kc = (lane & 3) * 16;
      bf16x8_t t0 = *(const bf16x8_t*)&tl[m2 * 72 + kc];
      bf16x8_t t1 = *(const bf16x8_t*)&tl[m2 * 72 + kc + 8];
      unsigned short* ap = act + (size_t)(rowBase + m2) * 1024 + cb + kc;
      *(bf16x8_t*)ap = t0;
      *(bf16x8_t*)(ap + 8) = t1;
    }

#pragma unroll
    for (int ks = 0; ks < 2; ++ks) {
      bf16x8_t at = *(const bf16x8_t*)&tl[fr * 72 + ks * 32 + quad * 8];
#pragma unroll
      for (int n = 0; n < 4; n++) {
        bf16x8_t bu = *(const bf16x8_t*)&Un[(size_t)(n * 16 + fr) * 1024 + cb +
                                            ks * 32 + quad * 8];
        uacc[n] = __builtin_amdgcn_mfma_f32_16x16x32_bf16(at, bu, uacc[n], 0, 0, 0);
      }
    }
  }

  {
    float* up = &upart[w * 16 * 68];
#pragma unroll
    for (int n = 0; n < 4; n++)
#pragma unroll
      for (int r = 0; r < 4; r++)
        up[(quad * 4 + r) * 68 + n * 16 + fr] = uacc[n][r];
  }
  __syncthreads();
  {
    int m = tid >> 4;
    int c0 = (tid & 15) * 4;
    f32x4_t s = {0.f, 0.f, 0.f, 0.f};
#pragma unroll
    for (int wv = 0; wv < 4; wv++)
      s += *(const f32x4_t*)&upart[wv * 16 * 68 + m * 68 + c0];
    u16x4_t o = { f2bf(s[0]), f2bf(s[1]), f2bf(s[2]), f2bf(s[3]) };
    *(u16x4_t*)&u_out[(size_t)(rowBase + m) * 64 + c0] = o;
  }
}

// ---------------------------------------------------------------------------
// Final layer: out = h @ V^T + b (fp32), K = 64 (r4's gemm_bt<1,0,1>).
__global__ __launch_bounds__(256, 2) void k_final(
    const unsigned short* __restrict__ A, const unsigned short* __restrict__ B,
    const float* __restrict__ bias, float* __restrict__ Cout) {
  __shared__ unsigned short As[128 * 64];
  __shared__ unsigned short Bs[128 * 64];

  const int tid = threadIdx.x;
  const int lane = tid & 63;
  const int w = tid >> 6;
  const int wrow0 = (w & 1) * 64;
  const int wcol0 = (w >> 1) * 64;
  const int rowBase = blockIdx.y * 128;
  const int colBase = blockIdx.x * 128;

  const int rl = lane >> 3;
  const int kbg = (lane & 7) ^ rl;
  const int fr = lane & 15;
  const int quad = lane >> 4;

  f32x4_t acc[4][4];
#pragma unroll
  for (int i = 0; i < 4; i++)
#pragma unroll
    for (int j = 0; j < 4; j++) acc[i][j] = f32x4_t{0.f, 0.f, 0.f, 0.f};

  __syncthreads();
#pragma unroll
  for (int jj = 0; jj < 4; ++jj) {
    int tr = w * 32 + jj * 8 + rl;
    const unsigned short* ga = A + (size_t)(rowBase + tr) * 64 + kbg * 8;
    const unsigned short* gb = B + (size_t)(colBase + tr) * 64 + kbg * 8;
    __builtin_amdgcn_global_load_lds(
        (const __attribute__((address_space(1))) void*)ga,
        (__attribute__((address_space(3))) void*)&As[(w * 32 + jj * 8) * 64],
        16, 0, 0);
    __builtin_amdgcn_global_load_lds(
        (const __attribute__((address_space(1))) void*)gb,
        (__attribute__((address_space(3))) void*)&Bs[(w * 32 + jj * 8) * 64],
        16, 0, 0);
  }
  __syncthreads();

#pragma unroll
  for (int ks = 0; ks < 2; ++ks) {
    bf16x8_t a[4], b[4];
#pragma unroll
    for (int i = 0; i < 4; i++) {
      int m = wrow0 + i * 16 + fr;
      int slot = (ks * 4 + quad) ^ (m & 7);
      a[i] = *(const bf16x8_t*)&As[m * 64 + slot * 8];
    }
#pragma unroll
    for (int j = 0; j < 4; j++) {
      int n = wcol0 + j * 16 + fr;
      int slot = (ks * 4 + quad) ^ (n & 7);
      b[j] = *(const bf16x8_t*)&Bs[n * 64 + slot * 8];
    }
#pragma unroll
    for (int i = 0; i < 4; i++)
#pragma unroll
      for (int j = 0; j < 4; j++)
        acc[i][j] = __builtin_amdgcn_mfma_f32_16x16x32_bf16(a[i], b[j],
                                                            acc[i][j], 0, 0, 0);
  }

#pragma unroll
  for (int j = 0; j < 4; j++) {
    int col = colBase + wcol0 + j * 16 + fr;
    float bv = bias[col];
#pragma unroll
    for (int i = 0; i < 4; i++) {
#pragma unroll
      for (int r = 0; r < 4; r++) {
        int row = rowBase + wrow0 + i * 16 + quad * 4 + r;
        Cout[(size_t)row * 1024 + col] = acc[i][j][r] + bv;
      }
    }
  }
}

// ---------------------------------------------------------------------------
extern "C" void kernel_launch(void* const* d_in, const int* in_sizes, int n_in,
                              void* d_out, int out_size, void* d_ws,
                              size_t ws_size, hipStream_t stream) {
  const float* x = (const float*)d_in[0];
  const float* Wm[3] = {(const float*)d_in[1], (const float*)d_in[6], (const float*)d_in[11]};
  const float* bm[3] = {(const float*)d_in[2], (const float*)d_in[7], (const float*)d_in[12]};
  const float* U[3]  = {(const float*)d_in[3], (const float*)d_in[8], (const float*)d_in[13]};
  const float* V[3]  = {(const float*)d_in[4], (const float*)d_in[9], (const float*)d_in[14]};
  const float* bs[3] = {(const float*)d_in[5], (const float*)d_in[10], (const float*)d_in[15]};

  char* p = (char*)d_ws;
  unsigned short* xb = (unsigned short*)p;  p += 8192UL * 1024 * 2;
  unsigned short* act = (unsigned short*)p; p += 8192UL * 1024 * 2;
  unsigned short* Wmb[3];
  for (int l = 0; l < 3; l++) { Wmb[l] = (unsigned short*)p; p += 4096UL * 1024 * 2; }
  unsigned short* Ub[3];
  for (int l = 0; l < 3; l++) { Ub[l] = (unsigned short*)p; p += 64UL * 1024 * 2; }
  unsigned short* Vb[3];
  for (int l = 0; l < 3; l++) { Vb[l] = (unsigned short*)p; p += 1024UL * 64 * 2; }
  unsigned short* hb = (unsigned short*)p;  p += 8192UL * 64 * 2;
  unsigned short* ug = (unsigned short*)p;  p += 8192UL * 64 * 2;
  float* ug_part = (float*)p;               p += 4UL * 8192 * 64 * 4;

  // Dispatch 1: critical-path conversions only (x, Wm0, U0) — 74 MB
  CvtSeg c0;
  c0.src[0] = x;     c0.dst[0] = xb;
  c0.src[1] = Wm[0]; c0.dst[1] = Wmb[0];
  c0.src[2] = U[0];  c0.dst[2] = Ub[0];
  c0.bstart[0] = 0; c0.bstart[1] = 8192; c0.bstart[2] = 12288; c0.bstart[3] = 12352;
  k_cvt<<<12352, 256, 0, stream>>>(c0);

  // layer 0 u: x @ U0^T via split-K + reduce
  u_splitk<<<dim3(4, 64), 256, 0, stream>>>(xb, Ub[0], ug_part);
  u_reduce_k<<<512, 256, 0, stream>>>(ug_part, ug);

  // cvt tables for the work appended to each hyper dispatch
  CvtSeg ch[3];
  // hyper-0 extras: Wm1, U1, V0 (4224 blocks)
  ch[0].src[0] = Wm[1]; ch[0].dst[0] = Wmb[1];
  ch[0].src[1] = U[1];  ch[0].dst[1] = Ub[1];
  ch[0].src[2] = V[0];  ch[0].dst[2] = Vb[0];
  ch[0].bstart[0] = 0; ch[0].bstart[1] = 4096; ch[0].bstart[2] = 4160; ch[0].bstart[3] = 4224;
  // hyper-1 extras: Wm2, U2, V1 (4224 blocks)
  ch[1].src[0] = Wm[2]; ch[1].dst[0] = Wmb[2];
  ch[1].src[1] = U[2];  ch[1].dst[1] = Ub[2];
  ch[1].src[2] = V[1];  ch[1].dst[2] = Vb[1];
  ch[1].bstart[0] = 0; ch[1].bstart[1] = 4096; ch[1].bstart[2] = 4160; ch[1].bstart[3] = 4224;
  // hyper-2 extras: V2 only (64 blocks)
  ch[2].src[0] = V[2]; ch[2].dst[0] = Vb[2];
  ch[2].src[1] = V[2]; ch[2].dst[1] = Vb[2];   // unused (bstart collapse)
  ch[2].src[2] = V[2]; ch[2].dst[2] = Vb[2];   // unused
  ch[2].bstart[0] = 0; ch[2].bstart[1] = 64; ch[2].bstart[2] = 64; ch[2].bstart[3] = 64;

  const int hyperGrid[3] = {2048 + 4224, 2048 + 4224, 2048 + 64};

  const unsigned short* cur = xb;
  for (int l = 0; l < 3; l++) {
    // fused: h = einsum('br,brs->bs', u, cur@Wm^T + bm)  [+ appended cvt]
    k_hyper<<<hyperGrid[l], 256, 0, stream>>>(cur, Wmb[l], ug, bm[l], hb, ch[l]);
    if (l < 2) {
      // act = relu(h@V^T + b); u(next) = act @ U[l+1]^T
      vu_fused<<<512, 256, 0, stream>>>(hb, Vb[l], bs[l], Ub[l + 1], act, ug);
      cur = act;
    } else {
      k_final<<<dim3(8, 64), 256, 0, stream>>>(hb, Vb[2], bs[2], (float*)d_out);
    }
  }
}

// Round 9
// 407.487 us; speedup vs baseline: 2.4311x; 1.0204x over previous
//
#include <hip/hip_runtime.h>
#include <stdint.h>

typedef short bf16x8_t __attribute__((ext_vector_type(8)));
typedef short bf16x4_t __attribute__((ext_vector_type(4)));
typedef float f32x4_t __attribute__((ext_vector_type(4)));
typedef unsigned short u16x4_t __attribute__((ext_vector_type(4)));
typedef unsigned short u16x8_t __attribute__((ext_vector_type(8)));

#define DEV static __device__ __forceinline__

DEV float bf2f(unsigned short u) {
  union { unsigned int i; float f; } v; v.i = ((unsigned int)u) << 16; return v.f;
}
DEV unsigned short f2bf(float f) {
  union { float f; unsigned int i; } v; v.f = f;
  unsigned int x = v.i;
  unsigned int lsb = (x >> 16) & 1u;
  x += 0x7fffu + lsb;
  return (unsigned short)(x >> 16);
}

// Up to 3 cvt segments; boundaries in blocks of 256 vec4s (block-uniform).
struct CvtSeg {
  const float* src[3];
  unsigned short* dst[3];
  int bstart[4];   // bstart[0]=0; bstart[3]=total blocks
};

DEV void cvt_block(const CvtSeg& cs, int vb, int tid) {
  int seg = (vb >= cs.bstart[1] ? 1 : 0) + (vb >= cs.bstart[2] ? 1 : 0);
  int local = (vb - cs.bstart[seg]) * 256 + tid;
  float4 v = ((const float4*)cs.src[seg])[local];
  u16x4_t o = { f2bf(v.x), f2bf(v.y), f2bf(v.z), f2bf(v.w) };
  *(u16x4_t*)&cs.dst[seg][local * 4] = o;
}

// ---------------------------------------------------------------------------
// Dispatch 1: convert Wm0 + U0 only (critical path for xu_fused / hyper-0)
__global__ __launch_bounds__(256) void k_cvt(CvtSeg cs) {
  cvt_block(cs, blockIdx.x, threadIdx.x);
}

// ---------------------------------------------------------------------------
// xu_fused: converts x (fp32 -> bf16 in xb) AND computes u0 = x @ U0^T, using
// vu_fused's proven skeleton. Block = 16 sample rows, 4 waves; wave w owns
// k-cols [w*256, w*256+256) in 4 chunks of 64: load fp32 -> cvt -> store xb +
// LDS A-layout -> MFMA vs U0 accumulating u partials -> cross-wave reduce.
__global__ __launch_bounds__(256, 2) void xu_fused(
    const float* __restrict__ x,            // [8192 x 1024] fp32
    const unsigned short* __restrict__ U0,  // [64 x 1024] bf16
    unsigned short* __restrict__ xb,        // [8192 x 1024] bf16 out
    unsigned short* __restrict__ u_out) {   // [8192 x 64] bf16 out
  __shared__ unsigned short tlds[4 * 16 * 72];  // per-wave x chunk [16][72]
  __shared__ float upart[4 * 16 * 68];          // per-wave u partial [16][68]

  const int tid = threadIdx.x;
  const int lane = tid & 63;
  const int w = tid >> 6;
  const int fr = lane & 15;
  const int quad = lane >> 4;
  const int rowBase = blockIdx.x * 16;

  unsigned short* tl = &tlds[w * 16 * 72];
  const int m2 = lane >> 2;          // row within the 16-row block
  const int kc = (lane & 3) * 16;    // 16-col sub-chunk

  f32x4_t uacc[4];
#pragma unroll
  for (int n = 0; n < 4; n++) uacc[n] = f32x4_t{0.f, 0.f, 0.f, 0.f};

  for (int it = 0; it < 4; ++it) {
    const int cb = w * 256 + it * 64;  // k-chunk base

    // load x[16][64] fp32 chunk, convert, stage to LDS + store xb
    {
      const float* xp = x + (size_t)(rowBase + m2) * 1024 + cb + kc;
      float4 v0 = *(const float4*)(xp);
      float4 v1 = *(const float4*)(xp + 4);
      float4 v2 = *(const float4*)(xp + 8);
      float4 v3 = *(const float4*)(xp + 12);
      u16x8_t o0 = { f2bf(v0.x), f2bf(v0.y), f2bf(v0.z), f2bf(v0.w),
                     f2bf(v1.x), f2bf(v1.y), f2bf(v1.z), f2bf(v1.w) };
      u16x8_t o1 = { f2bf(v2.x), f2bf(v2.y), f2bf(v2.z), f2bf(v2.w),
                     f2bf(v3.x), f2bf(v3.y), f2bf(v3.z), f2bf(v3.w) };
      *(u16x8_t*)&tl[m2 * 72 + kc] = o0;
      *(u16x8_t*)&tl[m2 * 72 + kc + 8] = o1;
      unsigned short* xo = xb + (size_t)(rowBase + m2) * 1024 + cb + kc;
      *(u16x8_t*)xo = o0;
      *(u16x8_t*)(xo + 8) = o1;
    }

    // u += x_chunk @ U0^T (K = this 64-col chunk)
#pragma unroll
    for (int ks = 0; ks < 2; ++ks) {
      bf16x8_t at = *(const bf16x8_t*)&tl[fr * 72 + ks * 32 + quad * 8];
#pragma unroll
      for (int n = 0; n < 4; n++) {
        bf16x8_t bu = *(const bf16x8_t*)&U0[(size_t)(n * 16 + fr) * 1024 + cb +
                                            ks * 32 + quad * 8];
        uacc[n] = __builtin_amdgcn_mfma_f32_16x16x32_bf16(at, bu, uacc[n], 0, 0, 0);
      }
    }
  }

  // cross-wave reduction of u partials
  {
    float* up = &upart[w * 16 * 68];
#pragma unroll
    for (int n = 0; n < 4; n++)
#pragma unroll
      for (int r = 0; r < 4; r++)
        up[(quad * 4 + r) * 68 + n * 16 + fr] = uacc[n][r];
  }
  __syncthreads();
  {
    int m = tid >> 4;
    int c0 = (tid & 15) * 4;
    f32x4_t s = {0.f, 0.f, 0.f, 0.f};
#pragma unroll
    for (int wv = 0; wv < 4; wv++)
      s += *(const f32x4_t*)&upart[wv * 16 * 68 + m * 68 + c0];
    u16x4_t o = { f2bf(s[0]), f2bf(s[1]), f2bf(s[2]), f2bf(s[3]) };
    *(u16x4_t*)&u_out[(size_t)(rowBase + m) * 64 + c0] = o;
  }
}

// ---------------------------------------------------------------------------
// Fused hyper-GEMM + per-sample contraction (col' = s*64+r permutation),
// PLUS appended cvt blocks (blockIdx.x >= 2048) converting the NEXT layer's
// weights while the GEMM runs.
__global__ __launch_bounds__(256, 2) void k_hyper(
    const unsigned short* __restrict__ A,    // [8192 x 1024] bf16
    const unsigned short* __restrict__ Wmb,  // [4096 x 1024] bf16
    const unsigned short* __restrict__ ug,   // [8192 x 64] bf16
    const float* __restrict__ bm,            // [4096] fp32
    unsigned short* __restrict__ h_out,      // [8192 x 64] bf16
    CvtSeg cs) {
  __shared__ unsigned short smem[16384];

  if (blockIdx.x >= 2048) {                  // appended conversion work
    cvt_block(cs, blockIdx.x - 2048, threadIdx.x);
    return;
  }

  unsigned short* As = smem;
  unsigned short* Bs = smem + 8192;
  const int K = 1024;

  const int tid = threadIdx.x;
  const int lane = tid & 63;
  const int w = tid >> 6;
  const int wrow0 = (w & 1) * 64;
  const int wcol0 = (w >> 1) * 64;
  const int bx = blockIdx.x & 31;
  const int by = blockIdx.x >> 5;
  const int rowBase = by * 128;
  const int colBase = bx * 128;

  const int rl = lane >> 3;
  const int kbg = (lane & 7) ^ rl;
  const int fr = lane & 15;
  const int quad = lane >> 4;

  f32x4_t acc[4][4];
#pragma unroll
  for (int i = 0; i < 4; i++)
#pragma unroll
    for (int j = 0; j < 4; j++) acc[i][j] = f32x4_t{0.f, 0.f, 0.f, 0.f};

  for (int kt = 0; kt < K; kt += 64) {
    __syncthreads();
#pragma unroll
    for (int jj = 0; jj < 4; ++jj) {
      int tr = w * 32 + jj * 8 + rl;
      int ct = colBase + tr;
      int pr = ((ct & 63) << 6) | (ct >> 6);  // Wm row for hyper-col ct
      const unsigned short* ga = A + (size_t)(rowBase + tr) * K + kt + kbg * 8;
      const unsigned short* gb = Wmb + (size_t)pr * K + kt + kbg * 8;
      __builtin_amdgcn_global_load_lds(
          (const __attribute__((address_space(1))) void*)ga,
          (__attribute__((address_space(3))) void*)&As[(w * 32 + jj * 8) * 64],
          16, 0, 0);
      __builtin_amdgcn_global_load_lds(
          (const __attribute__((address_space(1))) void*)gb,
          (__attribute__((address_space(3))) void*)&Bs[(w * 32 + jj * 8) * 64],
          16, 0, 0);
    }
    __syncthreads();

#pragma unroll
    for (int ks = 0; ks < 2; ++ks) {
      bf16x8_t a[4], b[4];
#pragma unroll
      for (int i = 0; i < 4; i++) {
        int m = wrow0 + i * 16 + fr;
        int slot = (ks * 4 + quad) ^ (m & 7);
        a[i] = *(const bf16x8_t*)&As[m * 64 + slot * 8];
      }
#pragma unroll
      for (int j = 0; j < 4; j++) {
        int n = wcol0 + j * 16 + fr;
        int slot = (ks * 4 + quad) ^ (n & 7);
        b[j] = *(const bf16x8_t*)&Bs[n * 64 + slot * 8];
      }
#pragma unroll
      for (int i = 0; i < 4; i++)
#pragma unroll
        for (int j = 0; j < 4; j++)
          acc[i][j] = __builtin_amdgcn_mfma_f32_16x16x32_bf16(a[i], b[j],
                                                              acc[i][j], 0, 0, 0);
    }
  }

  // ---- fused contraction epilogue ----
  __syncthreads();

  // stage u transposed: u_t[r][row], stride 136 to spread banks
  {
    int row = tid >> 1;
    int c0 = (tid & 1) * 32;
    const unsigned short* up = ug + (size_t)(rowBase + row) * 64 + c0;
    bf16x8_t v0 = *(const bf16x8_t*)(up);
    bf16x8_t v1 = *(const bf16x8_t*)(up + 8);
    bf16x8_t v2 = *(const bf16x8_t*)(up + 16);
    bf16x8_t v3 = *(const bf16x8_t*)(up + 24);
#pragma unroll
    for (int m = 0; m < 8; m++) {
      smem[(c0 + m) * 136 + row] = (unsigned short)v0[m];
      smem[(c0 + 8 + m) * 136 + row] = (unsigned short)v1[m];
      smem[(c0 + 16 + m) * 136 + row] = (unsigned short)v2[m];
      smem[(c0 + 24 + m) * 136 + row] = (unsigned short)v3[m];
    }
  }
  __syncthreads();

  const int s = bx * 2 + (w >> 1);
  float bmv[4];
#pragma unroll
  for (int j = 0; j < 4; j++) bmv[j] = bm[(j * 16 + fr) * 64 + s];

#pragma unroll
  for (int i = 0; i < 4; i++) {
    int row0 = wrow0 + i * 16 + quad * 4;
    bf16x4_t uv[4];
#pragma unroll
    for (int j = 0; j < 4; j++)
      uv[j] = *(const bf16x4_t*)&smem[(j * 16 + fr) * 136 + row0];
#pragma unroll
    for (int r = 0; r < 4; r++) {
      float p = 0.f;
#pragma unroll
      for (int j = 0; j < 4; j++)
        p += bf2f((unsigned short)uv[j][r]) * (acc[i][j][r] + bmv[j]);
      p += __shfl_xor(p, 1, 64);
      p += __shfl_xor(p, 2, 64);
      p += __shfl_xor(p, 4, 64);
      p += __shfl_xor(p, 8, 64);
      if (fr == 0)
        h_out[(size_t)(rowBase + row0 + r) * 64 + s] = f2bf(p);
    }
  }
}

// ---------------------------------------------------------------------------
// Fused V-GEMM + next-layer u-GEMM (r4-proven).
__global__ __launch_bounds__(256, 2) void vu_fused(
    const unsigned short* __restrict__ h,    // [8192 x 64] bf16
    const unsigned short* __restrict__ Vb,   // [1024 x 64] bf16
    const float* __restrict__ bias,          // [1024] fp32
    const unsigned short* __restrict__ Un,   // [64 x 1024] bf16 (next U)
    unsigned short* __restrict__ act,        // [8192 x 1024] bf16
    unsigned short* __restrict__ u_out) {    // [8192 x 64] bf16
  __shared__ unsigned short tlds[4 * 16 * 72];
  __shared__ float upart[4 * 16 * 68];

  const int tid = threadIdx.x;
  const int lane = tid & 63;
  const int w = tid >> 6;
  const int fr = lane & 15;
  const int quad = lane >> 4;
  const int rowBase = blockIdx.x * 16;

  unsigned short* tl = &tlds[w * 16 * 72];

  bf16x8_t ah0 = *(const bf16x8_t*)&h[(size_t)(rowBase + fr) * 64 + quad * 8];
  bf16x8_t ah1 = *(const bf16x8_t*)&h[(size_t)(rowBase + fr) * 64 + 32 + quad * 8];

  f32x4_t uacc[4];
#pragma unroll
  for (int n = 0; n < 4; n++) uacc[n] = f32x4_t{0.f, 0.f, 0.f, 0.f};

  for (int it = 0; it < 4; ++it) {
    const int cb = w * 256 + it * 64;

    f32x4_t tacc[4];
#pragma unroll
    for (int nt = 0; nt < 4; nt++) {
      const unsigned short* vrow = Vb + (size_t)(cb + nt * 16 + fr) * 64;
      bf16x8_t b0 = *(const bf16x8_t*)&vrow[quad * 8];
      bf16x8_t b1 = *(const bf16x8_t*)&vrow[32 + quad * 8];
      f32x4_t z = {0.f, 0.f, 0.f, 0.f};
      z = __builtin_amdgcn_mfma_f32_16x16x32_bf16(ah0, b0, z, 0, 0, 0);
      tacc[nt] = __builtin_amdgcn_mfma_f32_16x16x32_bf16(ah1, b1, z, 0, 0, 0);
    }

#pragma unroll
    for (int nt = 0; nt < 4; nt++) {
      float bv = bias[cb + nt * 16 + fr];
#pragma unroll
      for (int r = 0; r < 4; r++) {
        float v = tacc[nt][r] + bv;
        v = v > 0.f ? v : 0.f;
        tl[(quad * 4 + r) * 72 + nt * 16 + fr] = f2bf(v);
      }
    }

    {
      int m2 = lane >> 2;
      int kc = (lane & 3) * 16;
      bf16x8_t t0 = *(const bf16x8_t*)&tl[m2 * 72 + kc];
      bf16x8_t t1 = *(const bf16x8_t*)&tl[m2 * 72 + kc + 8];
      unsigned short* ap = act + (size_t)(rowBase + m2) * 1024 + cb + kc;
      *(bf16x8_t*)ap = t0;
      *(bf16x8_t*)(ap + 8) = t1;
    }

#pragma unroll
    for (int ks = 0; ks < 2; ++ks) {
      bf16x8_t at = *(const bf16x8_t*)&tl[fr * 72 + ks * 32 + quad * 8];
#pragma unroll
      for (int n = 0; n < 4; n++) {
        bf16x8_t bu = *(const bf16x8_t*)&Un[(size_t)(n * 16 + fr) * 1024 + cb +
                                            ks * 32 + quad * 8];
        uacc[n] = __builtin_amdgcn_mfma_f32_16x16x32_bf16(at, bu, uacc[n], 0, 0, 0);
      }
    }
  }

  {
    float* up = &upart[w * 16 * 68];
#pragma unroll
    for (int n = 0; n < 4; n++)
#pragma unroll
      for (int r = 0; r < 4; r++)
        up[(quad * 4 + r) * 68 + n * 16 + fr] = uacc[n][r];
  }
  __syncthreads();
  {
    int m = tid >> 4;
    int c0 = (tid & 15) * 4;
    f32x4_t s = {0.f, 0.f, 0.f, 0.f};
#pragma unroll
    for (int wv = 0; wv < 4; wv++)
      s += *(const f32x4_t*)&upart[wv * 16 * 68 + m * 68 + c0];
    u16x4_t o = { f2bf(s[0]), f2bf(s[1]), f2bf(s[2]), f2bf(s[3]) };
    *(u16x4_t*)&u_out[(size_t)(rowBase + m) * 64 + c0] = o;
  }
}

// ---------------------------------------------------------------------------
// Final layer: out = h @ V^T + b (fp32), K = 64.
__global__ __launch_bounds__(256, 2) void k_final(
    const unsigned short* __restrict__ A, const unsigned short* __restrict__ B,
    const float* __restrict__ bias, float* __restrict__ Cout) {
  __shared__ unsigned short As[128 * 64];
  __shared__ unsigned short Bs[128 * 64];

  const int tid = threadIdx.x;
  const int lane = tid & 63;
  const int w = tid >> 6;
  const int wrow0 = (w & 1) * 64;
  const int wcol0 = (w >> 1) * 64;
  const int rowBase = blockIdx.y * 128;
  const int colBase = blockIdx.x * 128;

  const int rl = lane >> 3;
  const int kbg = (lane & 7) ^ rl;
  const int fr = lane & 15;
  const int quad = lane >> 4;

  f32x4_t acc[4][4];
#pragma unroll
  for (int i = 0; i < 4; i++)
#pragma unroll
    for (int j = 0; j < 4; j++) acc[i][j] = f32x4_t{0.f, 0.f, 0.f, 0.f};

  __syncthreads();
#pragma unroll
  for (int jj = 0; jj < 4; ++jj) {
    int tr = w * 32 + jj * 8 + rl;
    const unsigned short* ga = A + (size_t)(rowBase + tr) * 64 + kbg * 8;
    const unsigned short* gb = B + (size_t)(colBase + tr) * 64 + kbg * 8;
    __builtin_amdgcn_global_load_lds(
        (const __attribute__((address_space(1))) void*)ga,
        (__attribute__((address_space(3))) void*)&As[(w * 32 + jj * 8) * 64],
        16, 0, 0);
    __builtin_amdgcn_global_load_lds(
        (const __attribute__((address_space(1))) void*)gb,
        (__attribute__((address_space(3))) void*)&Bs[(w * 32 + jj * 8) * 64],
        16, 0, 0);
  }
  __syncthreads();

#pragma unroll
  for (int ks = 0; ks < 2; ++ks) {
    bf16x8_t a[4], b[4];
#pragma unroll
    for (int i = 0; i < 4; i++) {
      int m = wrow0 + i * 16 + fr;
      int slot = (ks * 4 + quad) ^ (m & 7);
      a[i] = *(const bf16x8_t*)&As[m * 64 + slot * 8];
    }
#pragma unroll
    for (int j = 0; j < 4; j++) {
      int n = wcol0 + j * 16 + fr;
      int slot = (ks * 4 + quad) ^ (n & 7);
      b[j] = *(const bf16x8_t*)&Bs[n * 64 + slot * 8];
    }
#pragma unroll
    for (int i = 0; i < 4; i++)
#pragma unroll
      for (int j = 0; j < 4; j++)
        acc[i][j] = __builtin_amdgcn_mfma_f32_16x16x32_bf16(a[i], b[j],
                                                            acc[i][j], 0, 0, 0);
  }

#pragma unroll
  for (int j = 0; j < 4; j++) {
    int col = colBase + wcol0 + j * 16 + fr;
    float bv = bias[col];
#pragma unroll
    for (int i = 0; i < 4; i++) {
#pragma unroll
      for (int r = 0; r < 4; r++) {
        int row = rowBase + wrow0 + i * 16 + quad * 4 + r;
        Cout[(size_t)row * 1024 + col] = acc[i][j][r] + bv;
      }
    }
  }
}

// ---------------------------------------------------------------------------
extern "C" void kernel_launch(void* const* d_in, const int* in_sizes, int n_in,
                              void* d_out, int out_size, void* d_ws,
                              size_t ws_size, hipStream_t stream) {
  const float* x = (const float*)d_in[0];
  const float* Wm[3] = {(const float*)d_in[1], (const float*)d_in[6], (const float*)d_in[11]};
  const float* bm[3] = {(const float*)d_in[2], (const float*)d_in[7], (const float*)d_in[12]};
  const float* U[3]  = {(const float*)d_in[3], (const float*)d_in[8], (const float*)d_in[13]};
  const float* V[3]  = {(const float*)d_in[4], (const float*)d_in[9], (const float*)d_in[14]};
  const float* bs[3] = {(const float*)d_in[5], (const float*)d_in[10], (const float*)d_in[15]};

  char* p = (char*)d_ws;
  unsigned short* xb = (unsigned short*)p;  p += 8192UL * 1024 * 2;
  unsigned short* act = (unsigned short*)p; p += 8192UL * 1024 * 2;
  unsigned short* Wmb[3];
  for (int l = 0; l < 3; l++) { Wmb[l] = (unsigned short*)p; p += 4096UL * 1024 * 2; }
  unsigned short* Ub[3];
  for (int l = 0; l < 3; l++) { Ub[l] = (unsigned short*)p; p += 64UL * 1024 * 2; }
  unsigned short* Vb[3];
  for (int l = 0; l < 3; l++) { Vb[l] = (unsigned short*)p; p += 1024UL * 64 * 2; }
  unsigned short* hb = (unsigned short*)p;  p += 8192UL * 64 * 2;
  unsigned short* ug = (unsigned short*)p;  p += 8192UL * 64 * 2;

  // Dispatch 1: convert Wm0 + U0 (38 MB read) — the only serial conversions
  CvtSeg c0;
  c0.src[0] = Wm[0]; c0.dst[0] = Wmb[0];
  c0.src[1] = U[0];  c0.dst[1] = Ub[0];
  c0.src[2] = U[0];  c0.dst[2] = Ub[0];   // unused (bstart collapse)
  c0.bstart[0] = 0; c0.bstart[1] = 4096; c0.bstart[2] = 4160; c0.bstart[3] = 4160;
  k_cvt<<<4160, 256, 0, stream>>>(c0);

  // Dispatch 2: x cvt + u0 = x @ U0^T, fused (writes xb and ug)
  xu_fused<<<512, 256, 0, stream>>>(x, Ub[0], xb, ug);

  // cvt tables for the work appended to each hyper dispatch
  CvtSeg ch[3];
  ch[0].src[0] = Wm[1]; ch[0].dst[0] = Wmb[1];
  ch[0].src[1] = U[1];  ch[0].dst[1] = Ub[1];
  ch[0].src[2] = V[0];  ch[0].dst[2] = Vb[0];
  ch[0].bstart[0] = 0; ch[0].bstart[1] = 4096; ch[0].bstart[2] = 4160; ch[0].bstart[3] = 4224;
  ch[1].src[0] = Wm[2]; ch[1].dst[0] = Wmb[2];
  ch[1].src[1] = U[2];  ch[1].dst[1] = Ub[2];
  ch[1].src[2] = V[1];  ch[1].dst[2] = Vb[1];
  ch[1].bstart[0] = 0; ch[1].bstart[1] = 4096; ch[1].bstart[2] = 4160; ch[1].bstart[3] = 4224;
  ch[2].src[0] = V[2]; ch[2].dst[0] = Vb[2];
  ch[2].src[1] = V[2]; ch[2].dst[1] = Vb[2];   // unused
  ch[2].src[2] = V[2]; ch[2].dst[2] = Vb[2];   // unused
  ch[2].bstart[0] = 0; ch[2].bstart[1] = 64; ch[2].bstart[2] = 64; ch[2].bstart[3] = 64;

  const int hyperGrid[3] = {2048 + 4224, 2048 + 4224, 2048 + 64};

  const unsigned short* cur = xb;
  for (int l = 0; l < 3; l++) {
    // fused: h = einsum('br,brs->bs', u, cur@Wm^T + bm)  [+ appended cvt]
    k_hyper<<<hyperGrid[l], 256, 0, stream>>>(cur, Wmb[l], ug, bm[l], hb, ch[l]);
    if (l < 2) {
      // act = relu(h@V^T + b); u(next) = act @ U[l+1]^T
      vu_fused<<<512, 256, 0, stream>>>(hb, Vb[l], bs[l], Ub[l + 1], act, ug);
      cur = act;
    } else {
      k_final<<<dim3(8, 64), 256, 0, stream>>>(hb, Vb[2], bs[2], (float*)d_out);
    }
  }
}